// Round 1
// baseline (17097.993 us; speedup 1.0000x reference)
//
#include <hip/hip_runtime.h>
#include <cstdint>
#include <cstddef>

#define Bx 2
#define Sx 1024
#define Dx 1024
#define Hx 16
#define Lx 4
#define FFx 2048
#define DKx 64
#define Mx (Bx * Sx)   // 2048 rows

// ---------------- embed + positional encoding (pe indexed by BATCH, per ref bug) ----------------
__global__ void embed_kernel(const int* __restrict__ tokens,
                             const float* __restrict__ emb,
                             float* __restrict__ x) {
  size_t i = (size_t)blockIdx.x * blockDim.x + threadIdx.x;  // over Mx*Dx
  if (i >= (size_t)Mx * Dx) return;
  int d = (int)(i % Dx);
  size_t bs = i / Dx;
  int b = (int)(bs / Sx);
  int tok = tokens[bs];
  int dd = d & ~1;  // even pair index (2i)
  float arg = (float)b * expf((float)dd * (-logf(10000.0f) / (float)Dx));
  float pe = (d & 1) ? cosf(arg) : sinf(arg);
  x[i] = emb[(size_t)tok * Dx + d] + pe;
}

// ---------------- classic 16x16 LDS-tiled fp32 GEMM: C = A[M,K] @ W[K,N] + bias, opt ReLU ----------------
template <bool RELU>
__global__ void gemm_bias(const float* __restrict__ A, const float* __restrict__ W,
                          const float* __restrict__ bias, float* __restrict__ C,
                          int M, int N, int K) {
  __shared__ float As[16][16];
  __shared__ float Ws[16][17];
  int tx = threadIdx.x, ty = threadIdx.y;
  int row = blockIdx.y * 16 + ty;
  int col = blockIdx.x * 16 + tx;
  float acc = 0.f;
  for (int k0 = 0; k0 < K; k0 += 16) {
    As[ty][tx] = A[(size_t)row * K + k0 + tx];
    Ws[ty][tx] = W[(size_t)(k0 + ty) * N + col];
    __syncthreads();
#pragma unroll
    for (int kk = 0; kk < 16; ++kk) acc += As[ty][kk] * Ws[kk][tx];
    __syncthreads();
  }
  acc += bias[col];
  if (RELU) acc = fmaxf(acc, 0.f);
  C[(size_t)row * N + col] = acc;
}

// ---------------- fused attention: one block per (b,h,query) ----------------
__global__ void attention_kernel(const float* __restrict__ Q, const float* __restrict__ K,
                                 const float* __restrict__ V, float* __restrict__ O) {
  int qi = blockIdx.x, h = blockIdx.y, b = blockIdx.z;
  int t = threadIdx.x;  // 256 threads
  __shared__ float qs[DKx];
  __shared__ float sc[Sx];
  __shared__ float red[256];
  __shared__ float part[4][DKx];

  const size_t base = ((size_t)b * Sx) * Dx + (size_t)h * DKx;  // (b, row=0, head h)
  if (t < DKx) qs[t] = Q[base + (size_t)qi * Dx + t];
  __syncthreads();

  // scores = q . k / sqrt(DK)
  for (int kk = t; kk < Sx; kk += 256) {
    const float* kr = K + base + (size_t)kk * Dx;
    float dacc = 0.f;
#pragma unroll
    for (int j = 0; j < DKx; ++j) dacc += qs[j] * kr[j];
    sc[kk] = dacc * 0.125f;  // 1/sqrt(64)
  }
  __syncthreads();

  // block max
  float m = -1e30f;
  for (int kk = t; kk < Sx; kk += 256) m = fmaxf(m, sc[kk]);
  red[t] = m;
  __syncthreads();
  for (int off = 128; off > 0; off >>= 1) {
    if (t < off) red[t] = fmaxf(red[t], red[t + off]);
    __syncthreads();
  }
  m = red[0];
  __syncthreads();

  // exp + block sum
  float s = 0.f;
  for (int kk = t; kk < Sx; kk += 256) {
    float e = expf(sc[kk] - m);
    sc[kk] = e;
    s += e;
  }
  red[t] = s;
  __syncthreads();
  for (int off = 128; off > 0; off >>= 1) {
    if (t < off) red[t] += red[t + off];
    __syncthreads();
  }
  float inv = 1.f / red[0];

  // AV: wave g handles keys kk ≡ g (mod 4); lane = output dim
  int dk = t & (DKx - 1), g = t >> 6;
  float acc = 0.f;
  for (int kk = g; kk < Sx; kk += 4) acc += sc[kk] * V[base + (size_t)kk * Dx + dk];
  part[g][dk] = acc;
  __syncthreads();
  if (t < DKx) {
    float r = (part[0][t] + part[1][t] + part[2][t] + part[3][t]) * inv;
    O[base + (size_t)qi * Dx + t] = r;
  }
}

// ---------------- fused residual add + LayerNorm (one block per row) ----------------
__global__ void add_ln_kernel(const float* __restrict__ x, const float* __restrict__ r,
                              const float* __restrict__ gamma, const float* __restrict__ beta,
                              float* __restrict__ out) {
  int row = blockIdx.x, t = threadIdx.x;  // 256 threads, D=1024 -> 4/thread
  __shared__ float red[256];
  const float* xr = x + (size_t)row * Dx;
  const float* rr = r + (size_t)row * Dx;
  float v[4];
  float s = 0.f;
#pragma unroll
  for (int i = 0; i < 4; ++i) {
    v[i] = xr[t + i * 256] + rr[t + i * 256];
    s += v[i];
  }
  red[t] = s;
  __syncthreads();
  for (int off = 128; off > 0; off >>= 1) {
    if (t < off) red[t] += red[t + off];
    __syncthreads();
  }
  float mu = red[0] * (1.f / Dx);
  __syncthreads();
  float vs = 0.f;
#pragma unroll
  for (int i = 0; i < 4; ++i) {
    float d = v[i] - mu;
    vs += d * d;
  }
  red[t] = vs;
  __syncthreads();
  for (int off = 128; off > 0; off >>= 1) {
    if (t < off) red[t] += red[t + off];
    __syncthreads();
  }
  float is = rsqrtf(red[0] * (1.f / Dx) + 1e-5f);
  float* orow = out + (size_t)row * Dx;
#pragma unroll
  for (int i = 0; i < 4; ++i) {
    int c = t + i * 256;
    orow[c] = (v[i] - mu) * is * gamma[c] + beta[c];
  }
}

extern "C" void kernel_launch(void* const* d_in, const int* in_sizes, int n_in,
                              void* d_out, int out_size, void* d_ws, size_t ws_size,
                              hipStream_t stream) {
  const int* tokens = (const int*)d_in[0];
  const float* emb = (const float*)d_in[1];
  const float* Wq = (const float*)d_in[2];
  const float* bq = (const float*)d_in[3];
  const float* Wk = (const float*)d_in[4];
  const float* bk = (const float*)d_in[5];
  const float* Wv = (const float*)d_in[6];
  const float* bv = (const float*)d_in[7];
  const float* Wo = (const float*)d_in[8];
  const float* bo = (const float*)d_in[9];
  const float* W1 = (const float*)d_in[10];
  const float* b1 = (const float*)d_in[11];
  const float* W2 = (const float*)d_in[12];
  const float* b2 = (const float*)d_in[13];
  const float* gamma = (const float*)d_in[14];
  const float* beta = (const float*)d_in[15];

  float* ws = (float*)d_ws;
  const size_t XSZ = (size_t)Mx * Dx;  // 2M floats
  float* x = ws;            // [M,D]
  float* q = ws + XSZ;      // [M,D]
  float* k = ws + 2 * XSZ;  // [M,D]
  float* v = ws + 3 * XSZ;  // [M,D]
  float* o = ws + 4 * XSZ;  // [M,D]
  float* h1 = k;            // [M,FF] spans k..v (both free after attention)

  embed_kernel<<<((size_t)Mx * Dx + 255) / 256, 256, 0, stream>>>(tokens, emb, x);

  dim3 blk(16, 16);
  dim3 gD(Dx / 16, Mx / 16);
  dim3 gFF(FFx / 16, Mx / 16);

  for (int l = 0; l < Lx; ++l) {
    const float* Wq_l = Wq + (size_t)l * Dx * Dx;
    const float* Wk_l = Wk + (size_t)l * Dx * Dx;
    const float* Wv_l = Wv + (size_t)l * Dx * Dx;
    const float* Wo_l = Wo + (size_t)l * Dx * Dx;
    const float* W1_l = W1 + (size_t)l * Dx * FFx;
    const float* W2_l = W2 + (size_t)l * FFx * Dx;
    const float* bq_l = bq + (size_t)l * Dx;
    const float* bk_l = bk + (size_t)l * Dx;
    const float* bv_l = bv + (size_t)l * Dx;
    const float* bo_l = bo + (size_t)l * Dx;
    const float* b1_l = b1 + (size_t)l * FFx;
    const float* b2_l = b2 + (size_t)l * Dx;
    const float* g_l = gamma + (size_t)l * Dx;
    const float* be_l = beta + (size_t)l * Dx;

    gemm_bias<false><<<gD, blk, 0, stream>>>(x, Wq_l, bq_l, q, Mx, Dx, Dx);
    gemm_bias<false><<<gD, blk, 0, stream>>>(x, Wk_l, bk_l, k, Mx, Dx, Dx);
    gemm_bias<false><<<gD, blk, 0, stream>>>(x, Wv_l, bv_l, v, Mx, Dx, Dx);
    attention_kernel<<<dim3(Sx, Hx, Bx), 256, 0, stream>>>(q, k, v, o);
    gemm_bias<false><<<gD, blk, 0, stream>>>(o, Wo_l, bo_l, q, Mx, Dx, Dx);
    add_ln_kernel<<<Mx, 256, 0, stream>>>(x, q, g_l, be_l, x);
    gemm_bias<true><<<gFF, blk, 0, stream>>>(x, W1_l, b1_l, h1, Mx, FFx, Dx);
    gemm_bias<false><<<gD, blk, 0, stream>>>(h1, W2_l, b2_l, o, Mx, Dx, FFx);
    add_ln_kernel<<<Mx, 256, 0, stream>>>(x, o, g_l, be_l, x);
  }

  hipMemcpyAsync(d_out, x, XSZ * sizeof(float), hipMemcpyDeviceToDevice, stream);
}

// Round 2
// 2960.012 us; speedup vs baseline: 5.7763x; 5.7763x over previous
//
#include <hip/hip_runtime.h>
#include <cstdint>
#include <cstddef>

#define Bx 2
#define Sx 1024
#define Dx 1024
#define Hx 16
#define Lx 4
#define FFx 2048
#define DKx 64
#define Mx (Bx * Sx)   // 2048 rows

// ---------------- embed + positional encoding (pe indexed by BATCH, per ref bug) ----------------
__global__ void embed_kernel(const int* __restrict__ tokens,
                             const float* __restrict__ emb,
                             float* __restrict__ x) {
  size_t i = (size_t)blockIdx.x * blockDim.x + threadIdx.x;  // over Mx*Dx
  if (i >= (size_t)Mx * Dx) return;
  int d = (int)(i % Dx);
  size_t bs = i / Dx;
  int b = (int)(bs / Sx);
  int tok = tokens[bs];
  int dd = d & ~1;  // even pair index (2i)
  float arg = (float)b * expf((float)dd * (-logf(10000.0f) / (float)Dx));
  float pe = (d & 1) ? cosf(arg) : sinf(arg);
  x[i] = emb[(size_t)tok * Dx + d] + pe;
}

// ---------------- fp32 GEMM: C = A[M,K] @ W[K,N] + bias, opt ReLU ----------------
// 64x64 tile, 4x4 per thread register blocking, K-step 16.
template <bool RELU>
__global__ __launch_bounds__(256) void gemm_bias(const float* __restrict__ A,
                                                 const float* __restrict__ W,
                                                 const float* __restrict__ bias,
                                                 float* __restrict__ C,
                                                 int M, int N, int K) {
  __shared__ float AsT[16][68];  // [k][m] transposed A tile
  __shared__ float Ws[16][68];   // [k][n]
  int t = threadIdx.x;
  int tx = t & 15, ty = t >> 4;      // tx: n-block, ty: m-block
  int m0 = blockIdx.y * 64, n0 = blockIdx.x * 64;

  int lm = t >> 2;       // A loader: row in tile (0..63)
  int lk4 = t & 3;       // A loader: which float4 in k
  int lk = t >> 4;       // W loader: k row (0..15)
  int ln4 = t & 15;      // W loader: float4 col

  const float* Ap = A + (size_t)(m0 + lm) * K + 4 * lk4;
  const float* Wp = W + (size_t)lk * N + n0 + 4 * ln4;

  float acc[4][4] = {};

  for (int k0 = 0; k0 < K; k0 += 16) {
    float4 av = *(const float4*)(Ap + k0);
    float4 wv = *(const float4*)(Wp + (size_t)k0 * N);
    __syncthreads();
    AsT[4 * lk4 + 0][lm] = av.x;
    AsT[4 * lk4 + 1][lm] = av.y;
    AsT[4 * lk4 + 2][lm] = av.z;
    AsT[4 * lk4 + 3][lm] = av.w;
    *(float4*)&Ws[lk][4 * ln4] = wv;
    __syncthreads();
#pragma unroll
    for (int kk = 0; kk < 16; ++kk) {
      float4 a = *(const float4*)&AsT[kk][4 * ty];
      float4 b = *(const float4*)&Ws[kk][4 * tx];
      const float av_[4] = {a.x, a.y, a.z, a.w};
      const float bv_[4] = {b.x, b.y, b.z, b.w};
#pragma unroll
      for (int i = 0; i < 4; ++i)
#pragma unroll
        for (int j = 0; j < 4; ++j) acc[i][j] += av_[i] * bv_[j];
    }
  }

  float4 bb = *(const float4*)(bias + n0 + 4 * tx);
  const float bv_[4] = {bb.x, bb.y, bb.z, bb.w};
#pragma unroll
  for (int i = 0; i < 4; ++i) {
    float4 r;
    float* rp = (float*)&r;
#pragma unroll
    for (int j = 0; j < 4; ++j) {
      float v = acc[i][j] + bv_[j];
      if (RELU) v = fmaxf(v, 0.f);
      rp[j] = v;
    }
    *(float4*)&C[(size_t)(m0 + 4 * ty + i) * N + n0 + 4 * tx] = r;
  }
}

// ---------------- flash-style fused attention ----------------
// grid (S/64, H, B), block 256. Per block: 64 queries, loop over 64-key tiles.
__global__ __launch_bounds__(256) void attention_kernel(const float* __restrict__ Q,
                                                        const float* __restrict__ K,
                                                        const float* __restrict__ V,
                                                        float* __restrict__ O) {
  __shared__ float QsT[64][68];  // [j][q]
  __shared__ float KsT[64][68];  // [j][k]
  __shared__ float Vs[64][68];   // [k][d]
  __shared__ float ST[64][68];   // [k][q] scores then P
  __shared__ float mbuf[64], lbuf[64], rbuf[64];

  int t = threadIdx.x;
  int tx = t & 15, ty = t >> 4;  // tx: 4-col block (k or d), ty: 4-row block (q)
  int q0 = blockIdx.x * 64;
  int h = blockIdx.y, b = blockIdx.z;
  const size_t base = (size_t)b * Sx * Dx + (size_t)h * DKx;

  // load Q tile transposed
#pragma unroll
  for (int r = 0; r < 4; ++r) {
    int idx = t + r * 256;           // over 1024 float4
    int m = idx >> 4, j = (idx & 15) * 4;
    float4 v = *(const float4*)(Q + base + (size_t)(q0 + m) * Dx + j);
    QsT[j + 0][m] = v.x;
    QsT[j + 1][m] = v.y;
    QsT[j + 2][m] = v.z;
    QsT[j + 3][m] = v.w;
  }
  if (t < 64) {
    mbuf[t] = -1e30f;
    lbuf[t] = 0.f;
  }

  float o[4][4] = {};

  for (int kt = 0; kt < Sx / 64; ++kt) {
    int k0 = kt * 64;
    __syncthreads();  // previous tile's PV reads done
    // load K (transposed) and V (natural)
#pragma unroll
    for (int r = 0; r < 4; ++r) {
      int idx = t + r * 256;
      int m = idx >> 4, j = (idx & 15) * 4;
      float4 kv = *(const float4*)(K + base + (size_t)(k0 + m) * Dx + j);
      KsT[j + 0][m] = kv.x;
      KsT[j + 1][m] = kv.y;
      KsT[j + 2][m] = kv.z;
      KsT[j + 3][m] = kv.w;
      float4 vv = *(const float4*)(V + base + (size_t)(k0 + m) * Dx + j);
      *(float4*)&Vs[m][j] = vv;
    }
    __syncthreads();

    // scores: S[q][k] = sum_j QsT[j][q] * KsT[j][k]
    float s[4][4] = {};
#pragma unroll 8
    for (int j = 0; j < 64; ++j) {
      float4 a = *(const float4*)&QsT[j][4 * ty];
      float4 bq = *(const float4*)&KsT[j][4 * tx];
      const float av_[4] = {a.x, a.y, a.z, a.w};
      const float bv_[4] = {bq.x, bq.y, bq.z, bq.w};
#pragma unroll
      for (int i = 0; i < 4; ++i)
#pragma unroll
        for (int jj = 0; jj < 4; ++jj) s[i][jj] += av_[i] * bv_[jj];
    }
    // write scores transposed: ST[k][q]
#pragma unroll
    for (int i = 0; i < 4; ++i)
#pragma unroll
      for (int jj = 0; jj < 4; ++jj) ST[4 * tx + jj][4 * ty + i] = s[i][jj] * 0.125f;
    __syncthreads();

    // online softmax: 4 threads per q row
    {
      int r = t >> 2, g = t & 3;
      float sv[16];
      float tm = -1e30f;
#pragma unroll
      for (int i = 0; i < 16; ++i) {
        sv[i] = ST[g * 16 + i][r];
        tm = fmaxf(tm, sv[i]);
      }
      tm = fmaxf(tm, __shfl_xor(tm, 1));
      tm = fmaxf(tm, __shfl_xor(tm, 2));
      float m_old = mbuf[r];
      float m_new = fmaxf(m_old, tm);
      float ps = 0.f;
#pragma unroll
      for (int i = 0; i < 16; ++i) {
        float p = __expf(sv[i] - m_new);
        ST[g * 16 + i][r] = p;
        ps += p;
      }
      ps += __shfl_xor(ps, 1);
      ps += __shfl_xor(ps, 2);
      if (g == 0) {
        float rs = __expf(m_old - m_new);
        mbuf[r] = m_new;
        lbuf[r] = lbuf[r] * rs + ps;
        rbuf[r] = rs;
      }
    }
    __syncthreads();

    // PV: o[q][d] = o*rescale + sum_k ST[k][q] * Vs[k][d]
#pragma unroll
    for (int i = 0; i < 4; ++i) {
      float f = rbuf[4 * ty + i];
#pragma unroll
      for (int jj = 0; jj < 4; ++jj) o[i][jj] *= f;
    }
#pragma unroll 8
    for (int k = 0; k < 64; ++k) {
      float4 a = *(const float4*)&ST[k][4 * ty];
      float4 bq = *(const float4*)&Vs[k][4 * tx];
      const float av_[4] = {a.x, a.y, a.z, a.w};
      const float bv_[4] = {bq.x, bq.y, bq.z, bq.w};
#pragma unroll
      for (int i = 0; i < 4; ++i)
#pragma unroll
        for (int jj = 0; jj < 4; ++jj) o[i][jj] += av_[i] * bv_[jj];
    }
  }
  __syncthreads();

  // epilogue: divide by l, write out
#pragma unroll
  for (int i = 0; i < 4; ++i) {
    float inv = 1.f / lbuf[4 * ty + i];
    float4 r;
    r.x = o[i][0] * inv;
    r.y = o[i][1] * inv;
    r.z = o[i][2] * inv;
    r.w = o[i][3] * inv;
    *(float4*)&O[base + (size_t)(q0 + 4 * ty + i) * Dx + 4 * tx] = r;
  }
}

// ---------------- fused residual add + LayerNorm (one block per row) ----------------
__global__ void add_ln_kernel(const float* __restrict__ x, const float* __restrict__ r,
                              const float* __restrict__ gamma, const float* __restrict__ beta,
                              float* __restrict__ out) {
  int row = blockIdx.x, t = threadIdx.x;  // 256 threads, D=1024 -> 4/thread
  __shared__ float red[256];
  const float* xr = x + (size_t)row * Dx;
  const float* rr = r + (size_t)row * Dx;
  float v[4];
  float s = 0.f;
#pragma unroll
  for (int i = 0; i < 4; ++i) {
    v[i] = xr[t + i * 256] + rr[t + i * 256];
    s += v[i];
  }
  red[t] = s;
  __syncthreads();
  for (int off = 128; off > 0; off >>= 1) {
    if (t < off) red[t] += red[t + off];
    __syncthreads();
  }
  float mu = red[0] * (1.f / Dx);
  __syncthreads();
  float vs = 0.f;
#pragma unroll
  for (int i = 0; i < 4; ++i) {
    float d = v[i] - mu;
    vs += d * d;
  }
  red[t] = vs;
  __syncthreads();
  for (int off = 128; off > 0; off >>= 1) {
    if (t < off) red[t] += red[t + off];
    __syncthreads();
  }
  float is = rsqrtf(red[0] * (1.f / Dx) + 1e-5f);
  float* orow = out + (size_t)row * Dx;
#pragma unroll
  for (int i = 0; i < 4; ++i) {
    int c = t + i * 256;
    orow[c] = (v[i] - mu) * is * gamma[c] + beta[c];
  }
}

extern "C" void kernel_launch(void* const* d_in, const int* in_sizes, int n_in,
                              void* d_out, int out_size, void* d_ws, size_t ws_size,
                              hipStream_t stream) {
  const int* tokens = (const int*)d_in[0];
  const float* emb = (const float*)d_in[1];
  const float* Wq = (const float*)d_in[2];
  const float* bq = (const float*)d_in[3];
  const float* Wk = (const float*)d_in[4];
  const float* bk = (const float*)d_in[5];
  const float* Wv = (const float*)d_in[6];
  const float* bv = (const float*)d_in[7];
  const float* Wo = (const float*)d_in[8];
  const float* bo = (const float*)d_in[9];
  const float* W1 = (const float*)d_in[10];
  const float* b1 = (const float*)d_in[11];
  const float* W2 = (const float*)d_in[12];
  const float* b2 = (const float*)d_in[13];
  const float* gamma = (const float*)d_in[14];
  const float* beta = (const float*)d_in[15];

  float* ws = (float*)d_ws;
  const size_t XSZ = (size_t)Mx * Dx;  // 2M floats
  float* x = ws;            // [M,D]
  float* q = ws + XSZ;      // [M,D]
  float* k = ws + 2 * XSZ;  // [M,D]
  float* v = ws + 3 * XSZ;  // [M,D]
  float* o = ws + 4 * XSZ;  // [M,D]
  float* h1 = k;            // [M,FF] spans k..v (both free after attention)

  embed_kernel<<<((size_t)Mx * Dx + 255) / 256, 256, 0, stream>>>(tokens, emb, x);

  dim3 gD(Dx / 64, Mx / 64);
  dim3 gFF(FFx / 64, Mx / 64);

  for (int l = 0; l < Lx; ++l) {
    const float* Wq_l = Wq + (size_t)l * Dx * Dx;
    const float* Wk_l = Wk + (size_t)l * Dx * Dx;
    const float* Wv_l = Wv + (size_t)l * Dx * Dx;
    const float* Wo_l = Wo + (size_t)l * Dx * Dx;
    const float* W1_l = W1 + (size_t)l * Dx * FFx;
    const float* W2_l = W2 + (size_t)l * FFx * Dx;
    const float* bq_l = bq + (size_t)l * Dx;
    const float* bk_l = bk + (size_t)l * Dx;
    const float* bv_l = bv + (size_t)l * Dx;
    const float* bo_l = bo + (size_t)l * Dx;
    const float* b1_l = b1 + (size_t)l * FFx;
    const float* b2_l = b2 + (size_t)l * Dx;
    const float* g_l = gamma + (size_t)l * Dx;
    const float* be_l = beta + (size_t)l * Dx;

    gemm_bias<false><<<gD, 256, 0, stream>>>(x, Wq_l, bq_l, q, Mx, Dx, Dx);
    gemm_bias<false><<<gD, 256, 0, stream>>>(x, Wk_l, bk_l, k, Mx, Dx, Dx);
    gemm_bias<false><<<gD, 256, 0, stream>>>(x, Wv_l, bv_l, v, Mx, Dx, Dx);
    attention_kernel<<<dim3(Sx / 64, Hx, Bx), 256, 0, stream>>>(q, k, v, o);
    gemm_bias<false><<<gD, 256, 0, stream>>>(o, Wo_l, bo_l, q, Mx, Dx, Dx);
    add_ln_kernel<<<Mx, 256, 0, stream>>>(x, q, g_l, be_l, x);
    gemm_bias<true><<<gFF, 256, 0, stream>>>(x, W1_l, b1_l, h1, Mx, FFx, Dx);
    gemm_bias<false><<<gD, 256, 0, stream>>>(h1, W2_l, b2_l, o, Mx, Dx, FFx);
    add_ln_kernel<<<Mx, 256, 0, stream>>>(x, o, g_l, be_l, x);
  }

  hipMemcpyAsync(d_out, x, XSZ * sizeof(float), hipMemcpyDeviceToDevice, stream);
}

// Round 3
// 1447.658 us; speedup vs baseline: 11.8108x; 2.0447x over previous
//
#include <hip/hip_runtime.h>
#include <cstdint>
#include <cstddef>

#define Bx 2
#define Sx 1024
#define Dx 1024
#define Hx 16
#define Lx 4
#define FFx 2048
#define DKx 64
#define Mx (Bx * Sx)   // 2048 rows

typedef __attribute__((ext_vector_type(4))) float f32x4;
typedef __attribute__((ext_vector_type(8))) __bf16 bf16x8;
typedef __attribute__((ext_vector_type(4))) __bf16 bf16x4;

// ---------------- embed + positional encoding (pe indexed by BATCH, per ref bug) ----------------
__global__ void embed_kernel(const int* __restrict__ tokens,
                             const float* __restrict__ emb,
                             float* __restrict__ x) {
  size_t i = (size_t)blockIdx.x * blockDim.x + threadIdx.x;  // over Mx*Dx
  if (i >= (size_t)Mx * Dx) return;
  int d = (int)(i % Dx);
  size_t bs = i / Dx;
  int b = (int)(bs / Sx);
  int tok = tokens[bs];
  int dd = d & ~1;  // even pair index (2i)
  float arg = (float)b * expf((float)dd * (-logf(10000.0f) / (float)Dx));
  float pe = (d & 1) ? cosf(arg) : sinf(arg);
  x[i] = emb[(size_t)tok * Dx + d] + pe;
}

// ---------------- fp32 -> bf16 convert ----------------
__global__ void to_bf16_kernel(const float* __restrict__ x, __bf16* __restrict__ y, int n4) {
  int i = blockIdx.x * blockDim.x + threadIdx.x;
  if (i >= n4) return;
  float4 v = *(const float4*)(x + 4 * (size_t)i);
  bf16x4 o = {(__bf16)v.x, (__bf16)v.y, (__bf16)v.z, (__bf16)v.w};
  *(bf16x4*)(y + 4 * (size_t)i) = o;
}

// ---------------- W[K,N] fp32 -> Wt[N,K] bf16 (32x32 tile transpose) ----------------
__global__ void transpose_to_bf16(const float* __restrict__ W, __bf16* __restrict__ Wt,
                                  int K, int N) {
  __shared__ float tile[32][33];
  int tx = threadIdx.x, ty = threadIdx.y;  // 32 x 8
  int n0 = blockIdx.x * 32, k0 = blockIdx.y * 32;
#pragma unroll
  for (int i = 0; i < 4; ++i)
    tile[ty + 8 * i][tx] = W[(size_t)(k0 + ty + 8 * i) * N + n0 + tx];
  __syncthreads();
#pragma unroll
  for (int i = 0; i < 4; ++i)
    Wt[(size_t)(n0 + ty + 8 * i) * K + k0 + tx] = (__bf16)tile[tx][ty + 8 * i];
}

__global__ void concat3_kernel(const float* __restrict__ a, const float* __restrict__ b,
                               const float* __restrict__ c, float* __restrict__ out) {
  int i = blockIdx.x * 256 + threadIdx.x;  // 3072
  float v = (i < 1024) ? a[i] : ((i < 2048) ? b[i - 1024] : c[i - 2048]);
  out[i] = v;
}

// ---------------- bf16 MFMA GEMM: C = A[M,K] @ Bt[N,K]^T + bias ----------------
// Tile TM x 128, BK=32, 4 waves. global_load_lds width-16 staging (m97 structure).
__device__ __forceinline__ void gld_lds16(const void* g, void* l) {
  __builtin_amdgcn_global_load_lds(
      (const __attribute__((address_space(1))) void*)(uintptr_t)g,
      (__attribute__((address_space(3))) void*)(uintptr_t)l, 16, 0, 0);
}

template <int TM, bool RELU, typename OutT>
__global__ __launch_bounds__(256) void gemm_bt(const __bf16* __restrict__ A,
                                               const __bf16* __restrict__ Bt,
                                               const float* __restrict__ bias,
                                               OutT* __restrict__ C,
                                               int K, int ldc) {
  constexpr int MI = TM / 32;            // MFMA row-tiles per wave
  constexpr int NCH = (TM + 128) / 16;   // 1KB staging chunks per K-step
  __shared__ __align__(16) __bf16 lds[(TM + 128) * 32];
  const int t = threadIdx.x;
  const int w = t >> 6, lane = t & 63;
  const int m0 = blockIdx.y * TM, n0 = blockIdx.x * 128;
  const int lr = lane >> 2, lc = (lane & 3) * 8;  // staging: row-in-chunk, k-col

  f32x4 acc[MI][4] = {};

  const int WR = (w >> 1) * (TM / 2);
  const int WC = (w & 1) * 64;
  const __bf16* Abase = A + (size_t)m0 * K;
  const __bf16* Bbase = Bt + (size_t)n0 * K;

  for (int k0 = 0; k0 < K; k0 += 32) {
    __syncthreads();
#pragma unroll
    for (int c = 0; c < NCH / 4; ++c) {
      const int ch = c * 4 + w;
      const int r = ch * 16 + lr;
      const __bf16* g = (r < TM) ? (Abase + (size_t)r * K + k0 + lc)
                                 : (Bbase + (size_t)(r - TM) * K + k0 + lc);
      gld_lds16(g, (void*)(lds + ch * 512));
    }
    __syncthreads();
    bf16x8 af[MI], bfr[4];
#pragma unroll
    for (int i = 0; i < MI; ++i)
      af[i] = *(const bf16x8*)&lds[(WR + i * 16 + (lane & 15)) * 32 + (lane >> 4) * 8];
#pragma unroll
    for (int j = 0; j < 4; ++j)
      bfr[j] = *(const bf16x8*)&lds[(TM + WC + j * 16 + (lane & 15)) * 32 + (lane >> 4) * 8];
#pragma unroll
    for (int i = 0; i < MI; ++i)
#pragma unroll
      for (int j = 0; j < 4; ++j)
        acc[i][j] = __builtin_amdgcn_mfma_f32_16x16x32_bf16(af[i], bfr[j], acc[i][j], 0, 0, 0);
  }

  // epilogue: C/D layout col=lane&15, row=(lane>>4)*4+reg (m89/m91-verified)
  const int col0 = n0 + WC + (lane & 15);
#pragma unroll
  for (int j = 0; j < 4; ++j) {
    const int n = col0 + j * 16;
    const float bn = bias[n];
#pragma unroll
    for (int i = 0; i < MI; ++i) {
#pragma unroll
      for (int r = 0; r < 4; ++r) {
        const int m = m0 + WR + i * 16 + (lane >> 4) * 4 + r;
        float v = acc[i][j][r] + bn;
        if (RELU) v = fmaxf(v, 0.f);
        C[(size_t)m * ldc + n] = (OutT)v;
      }
    }
  }
}

// ---------------- flash-style fused attention (fp32), strided Q/K/V ----------------
__global__ __launch_bounds__(256) void attention_kernel(const float* __restrict__ Q,
                                                        const float* __restrict__ K,
                                                        const float* __restrict__ V,
                                                        float* __restrict__ O,
                                                        int ldq, int ldo) {
  __shared__ float QsT[64][68];  // [j][q]
  __shared__ float KsT[64][68];  // [j][k]
  __shared__ float Vs[64][68];   // [k][d]
  __shared__ float ST[64][68];   // [k][q] scores then P
  __shared__ float mbuf[64], lbuf[64], rbuf[64];

  int t = threadIdx.x;
  int tx = t & 15, ty = t >> 4;
  int q0 = blockIdx.x * 64;
  int h = blockIdx.y, b = blockIdx.z;
  const size_t base = (size_t)b * Sx * ldq + (size_t)h * DKx;
  const size_t baseo = (size_t)b * Sx * ldo + (size_t)h * DKx;

#pragma unroll
  for (int r = 0; r < 4; ++r) {
    int idx = t + r * 256;
    int m = idx >> 4, j = (idx & 15) * 4;
    float4 v = *(const float4*)(Q + base + (size_t)(q0 + m) * ldq + j);
    QsT[j + 0][m] = v.x;
    QsT[j + 1][m] = v.y;
    QsT[j + 2][m] = v.z;
    QsT[j + 3][m] = v.w;
  }
  if (t < 64) {
    mbuf[t] = -1e30f;
    lbuf[t] = 0.f;
  }

  float o[4][4] = {};

  for (int kt = 0; kt < Sx / 64; ++kt) {
    int k0 = kt * 64;
    __syncthreads();
#pragma unroll
    for (int r = 0; r < 4; ++r) {
      int idx = t + r * 256;
      int m = idx >> 4, j = (idx & 15) * 4;
      float4 kv = *(const float4*)(K + base + (size_t)(k0 + m) * ldq + j);
      KsT[j + 0][m] = kv.x;
      KsT[j + 1][m] = kv.y;
      KsT[j + 2][m] = kv.z;
      KsT[j + 3][m] = kv.w;
      float4 vv = *(const float4*)(V + base + (size_t)(k0 + m) * ldq + j);
      *(float4*)&Vs[m][j] = vv;
    }
    __syncthreads();

    float s[4][4] = {};
#pragma unroll 8
    for (int j = 0; j < 64; ++j) {
      float4 a = *(const float4*)&QsT[j][4 * ty];
      float4 bq = *(const float4*)&KsT[j][4 * tx];
      const float av_[4] = {a.x, a.y, a.z, a.w};
      const float bv_[4] = {bq.x, bq.y, bq.z, bq.w};
#pragma unroll
      for (int i = 0; i < 4; ++i)
#pragma unroll
        for (int jj = 0; jj < 4; ++jj) s[i][jj] += av_[i] * bv_[jj];
    }
#pragma unroll
    for (int i = 0; i < 4; ++i)
#pragma unroll
      for (int jj = 0; jj < 4; ++jj) ST[4 * tx + jj][4 * ty + i] = s[i][jj] * 0.125f;
    __syncthreads();

    {
      int r = t >> 2, g = t & 3;
      float sv[16];
      float tm = -1e30f;
#pragma unroll
      for (int i = 0; i < 16; ++i) {
        sv[i] = ST[g * 16 + i][r];
        tm = fmaxf(tm, sv[i]);
      }
      tm = fmaxf(tm, __shfl_xor(tm, 1));
      tm = fmaxf(tm, __shfl_xor(tm, 2));
      float m_old = mbuf[r];
      float m_new = fmaxf(m_old, tm);
      float ps = 0.f;
#pragma unroll
      for (int i = 0; i < 16; ++i) {
        float p = __expf(sv[i] - m_new);
        ST[g * 16 + i][r] = p;
        ps += p;
      }
      ps += __shfl_xor(ps, 1);
      ps += __shfl_xor(ps, 2);
      if (g == 0) {
        float rs = __expf(m_old - m_new);
        mbuf[r] = m_new;
        lbuf[r] = lbuf[r] * rs + ps;
        rbuf[r] = rs;
      }
    }
    __syncthreads();

#pragma unroll
    for (int i = 0; i < 4; ++i) {
      float f = rbuf[4 * ty + i];
#pragma unroll
      for (int jj = 0; jj < 4; ++jj) o[i][jj] *= f;
    }
#pragma unroll 8
    for (int k = 0; k < 64; ++k) {
      float4 a = *(const float4*)&ST[k][4 * ty];
      float4 bq = *(const float4*)&Vs[k][4 * tx];
      const float av_[4] = {a.x, a.y, a.z, a.w};
      const float bv_[4] = {bq.x, bq.y, bq.z, bq.w};
#pragma unroll
      for (int i = 0; i < 4; ++i)
#pragma unroll
        for (int jj = 0; jj < 4; ++jj) o[i][jj] += av_[i] * bv_[jj];
    }
  }
  __syncthreads();

#pragma unroll
  for (int i = 0; i < 4; ++i) {
    float inv = 1.f / lbuf[4 * ty + i];
    float4 r;
    r.x = o[i][0] * inv;
    r.y = o[i][1] * inv;
    r.z = o[i][2] * inv;
    r.w = o[i][3] * inv;
    *(float4*)&O[baseo + (size_t)(q0 + 4 * ty + i) * ldo + 4 * tx] = r;
  }
}

// ---------------- fused residual add + LayerNorm (one block per row) ----------------
__global__ void add_ln_kernel(const float* __restrict__ x, const float* __restrict__ r,
                              const float* __restrict__ gamma, const float* __restrict__ beta,
                              float* __restrict__ out) {
  int row = blockIdx.x, t = threadIdx.x;
  __shared__ float red[256];
  const float* xr = x + (size_t)row * Dx;
  const float* rr = r + (size_t)row * Dx;
  float v[4];
  float s = 0.f;
#pragma unroll
  for (int i = 0; i < 4; ++i) {
    v[i] = xr[t + i * 256] + rr[t + i * 256];
    s += v[i];
  }
  red[t] = s;
  __syncthreads();
  for (int off = 128; off > 0; off >>= 1) {
    if (t < off) red[t] += red[t + off];
    __syncthreads();
  }
  float mu = red[0] * (1.f / Dx);
  __syncthreads();
  float vs = 0.f;
#pragma unroll
  for (int i = 0; i < 4; ++i) {
    float d = v[i] - mu;
    vs += d * d;
  }
  red[t] = vs;
  __syncthreads();
  for (int off = 128; off > 0; off >>= 1) {
    if (t < off) red[t] += red[t + off];
    __syncthreads();
  }
  float is = rsqrtf(red[0] * (1.f / Dx) + 1e-5f);
  float* orow = out + (size_t)row * Dx;
#pragma unroll
  for (int i = 0; i < 4; ++i) {
    int c = t + i * 256;
    orow[c] = (v[i] - mu) * is * gamma[c] + beta[c];
  }
}

extern "C" void kernel_launch(void* const* d_in, const int* in_sizes, int n_in,
                              void* d_out, int out_size, void* d_ws, size_t ws_size,
                              hipStream_t stream) {
  const int* tokens = (const int*)d_in[0];
  const float* emb = (const float*)d_in[1];
  const float* Wq = (const float*)d_in[2];
  const float* bq = (const float*)d_in[3];
  const float* Wk = (const float*)d_in[4];
  const float* bk = (const float*)d_in[5];
  const float* Wv = (const float*)d_in[6];
  const float* bv = (const float*)d_in[7];
  const float* Wo = (const float*)d_in[8];
  const float* bo = (const float*)d_in[9];
  const float* W1 = (const float*)d_in[10];
  const float* b1 = (const float*)d_in[11];
  const float* W2 = (const float*)d_in[12];
  const float* b2 = (const float*)d_in[13];
  const float* gamma = (const float*)d_in[14];
  const float* beta = (const float*)d_in[15];

  const size_t M1 = 1024 * 1024;
  float* ws = (float*)d_ws;
  float* x = ws;                  // 2M f32
  float* qkv = ws + 2 * M1;       // [2048][3072] f32 (6M)
  float* o = ws + 8 * M1;         // 2M f32
  float* tmp = ws + 10 * M1;      // 2M f32
  __bf16* bfr = (__bf16*)(ws + 12 * M1);
  __bf16* xb = bfr;               // 2M bf16
  __bf16* ob = bfr + 2 * M1;      // 2M
  __bf16* h1b = bfr + 4 * M1;     // 4M  [2048][2048]
  __bf16* WqkvT = bfr + 8 * M1;   // 3M  [3072][1024]
  __bf16* WoT = bfr + 11 * M1;    // 1M  [1024][1024]
  __bf16* W1T = bfr + 12 * M1;    // 2M  [2048][1024]
  __bf16* W2T = bfr + 14 * M1;    // 2M  [1024][2048]
  float* bqkv = (float*)(bfr + 16 * M1);  // 3072 f32

  embed_kernel<<<((size_t)Mx * Dx + 255) / 256, 256, 0, stream>>>(tokens, emb, x);

  dim3 tb(32, 8);
  const int NB4 = (2 * M1 / 4 + 255) / 256;

  for (int l = 0; l < Lx; ++l) {
    const float* Wq_l = Wq + (size_t)l * Dx * Dx;
    const float* Wk_l = Wk + (size_t)l * Dx * Dx;
    const float* Wv_l = Wv + (size_t)l * Dx * Dx;
    const float* Wo_l = Wo + (size_t)l * Dx * Dx;
    const float* W1_l = W1 + (size_t)l * Dx * FFx;
    const float* W2_l = W2 + (size_t)l * FFx * Dx;
    const float* bo_l = bo + (size_t)l * Dx;
    const float* b1_l = b1 + (size_t)l * FFx;
    const float* b2_l = b2 + (size_t)l * Dx;
    const float* g_l = gamma + (size_t)l * Dx;
    const float* be_l = beta + (size_t)l * Dx;

    // weight prep (bf16, transposed)
    transpose_to_bf16<<<dim3(32, 32), tb, 0, stream>>>(Wq_l, WqkvT, Dx, Dx);
    transpose_to_bf16<<<dim3(32, 32), tb, 0, stream>>>(Wk_l, WqkvT + M1, Dx, Dx);
    transpose_to_bf16<<<dim3(32, 32), tb, 0, stream>>>(Wv_l, WqkvT + 2 * M1, Dx, Dx);
    transpose_to_bf16<<<dim3(32, 32), tb, 0, stream>>>(Wo_l, WoT, Dx, Dx);
    transpose_to_bf16<<<dim3(64, 32), tb, 0, stream>>>(W1_l, W1T, Dx, FFx);
    transpose_to_bf16<<<dim3(32, 64), tb, 0, stream>>>(W2_l, W2T, FFx, Dx);
    concat3_kernel<<<12, 256, 0, stream>>>(bq + (size_t)l * Dx, bk + (size_t)l * Dx,
                                           bv + (size_t)l * Dx, bqkv);

    // QKV fused GEMM: [2048,1024] x [1024,3072] -> qkv
    to_bf16_kernel<<<NB4, 256, 0, stream>>>(x, xb, 2 * M1 / 4);
    gemm_bt<128, false, float><<<dim3(3072 / 128, Mx / 128), 256, 0, stream>>>(
        xb, WqkvT, bqkv, qkv, Dx, 3072);

    attention_kernel<<<dim3(Sx / 64, Hx, Bx), 256, 0, stream>>>(
        qkv, qkv + 1024, qkv + 2048, o, 3072, Dx);

    // output projection
    to_bf16_kernel<<<NB4, 256, 0, stream>>>(o, ob, 2 * M1 / 4);
    gemm_bt<64, false, float><<<dim3(Dx / 128, Mx / 64), 256, 0, stream>>>(
        ob, WoT, bo_l, tmp, Dx, Dx);
    add_ln_kernel<<<Mx, 256, 0, stream>>>(x, tmp, g_l, be_l, x);

    // FF
    to_bf16_kernel<<<NB4, 256, 0, stream>>>(x, xb, 2 * M1 / 4);
    gemm_bt<128, true, __bf16><<<dim3(FFx / 128, Mx / 128), 256, 0, stream>>>(
        xb, W1T, b1_l, h1b, Dx, FFx);
    gemm_bt<64, false, float><<<dim3(Dx / 128, Mx / 64), 256, 0, stream>>>(
        h1b, W2T, b2_l, o, FFx, Dx);
    add_ln_kernel<<<Mx, 256, 0, stream>>>(x, o, g_l, be_l, x);
  }

  hipMemcpyAsync(d_out, x, 2 * M1 * sizeof(float), hipMemcpyDeviceToDevice, stream);
}

// Round 4
// 1011.225 us; speedup vs baseline: 16.9082x; 1.4316x over previous
//
#include <hip/hip_runtime.h>
#include <cstdint>
#include <cstddef>

#define Bx 2
#define Sx 1024
#define Dx 1024
#define Hx 16
#define Lx 4
#define FFx 2048
#define DKx 64
#define Mx (Bx * Sx)   // 2048 rows

typedef __attribute__((ext_vector_type(4))) float f32x4;
typedef __attribute__((ext_vector_type(8))) __bf16 bf16x8;
typedef __attribute__((ext_vector_type(4))) __bf16 bf16x4;

// ---------------- embed + positional encoding (pe indexed by BATCH, per ref bug) ----------------
__global__ void embed_kernel(const int* __restrict__ tokens,
                             const float* __restrict__ emb,
                             float* __restrict__ x, __bf16* __restrict__ xb) {
  size_t i = (size_t)blockIdx.x * blockDim.x + threadIdx.x;  // over Mx*Dx
  if (i >= (size_t)Mx * Dx) return;
  int d = (int)(i % Dx);
  size_t bs = i / Dx;
  int b = (int)(bs / Sx);
  int tok = tokens[bs];
  int dd = d & ~1;  // even pair index (2i)
  float arg = (float)b * expf((float)dd * (-logf(10000.0f) / (float)Dx));
  float pe = (d & 1) ? cosf(arg) : sinf(arg);
  float v = emb[(size_t)tok * Dx + d] + pe;
  x[i] = v;
  xb[i] = (__bf16)v;
}

// ---------------- W[K,N] fp32 -> Wt[N,K] bf16 (32x32 tile transpose) ----------------
__global__ void transpose_to_bf16(const float* __restrict__ W, __bf16* __restrict__ Wt,
                                  int K, int N) {
  __shared__ float tile[32][33];
  int tx = threadIdx.x, ty = threadIdx.y;  // 32 x 8
  int n0 = blockIdx.x * 32, k0 = blockIdx.y * 32;
#pragma unroll
  for (int i = 0; i < 4; ++i)
    tile[ty + 8 * i][tx] = W[(size_t)(k0 + ty + 8 * i) * N + n0 + tx];
  __syncthreads();
#pragma unroll
  for (int i = 0; i < 4; ++i)
    Wt[(size_t)(n0 + ty + 8 * i) * K + k0 + tx] = (__bf16)tile[tx][ty + 8 * i];
}

__global__ void concat3_kernel(const float* __restrict__ a, const float* __restrict__ b,
                               const float* __restrict__ c, float* __restrict__ out) {
  int i = blockIdx.x * 256 + threadIdx.x;  // 3072
  float v = (i < 1024) ? a[i] : ((i < 2048) ? b[i - 1024] : c[i - 2048]);
  out[i] = v;
}

// ---------------- bf16 MFMA GEMM: C = A[M,K] @ Bt[N,K]^T + bias ----------------
__device__ __forceinline__ void gld_lds16(const void* g, void* l) {
  __builtin_amdgcn_global_load_lds(
      (const __attribute__((address_space(1))) void*)(uintptr_t)g,
      (__attribute__((address_space(3))) void*)(uintptr_t)l, 16, 0, 0);
}

template <int TM, bool RELU, typename OutT>
__global__ __launch_bounds__(256) void gemm_bt(const __bf16* __restrict__ A,
                                               const __bf16* __restrict__ Bt,
                                               const float* __restrict__ bias,
                                               OutT* __restrict__ C,
                                               int K, int ldc) {
  constexpr int MI = TM / 32;            // MFMA row-tiles per wave
  constexpr int NCH = (TM + 128) / 16;   // 1KB staging chunks per K-step
  __shared__ __align__(16) __bf16 lds[(TM + 128) * 32];
  const int t = threadIdx.x;
  const int w = t >> 6, lane = t & 63;
  const int m0 = blockIdx.y * TM, n0 = blockIdx.x * 128;
  const int lr = lane >> 2, lc = (lane & 3) * 8;  // staging: row-in-chunk, k-col

  f32x4 acc[MI][4] = {};

  const int WR = (w >> 1) * (TM / 2);
  const int WC = (w & 1) * 64;
  const __bf16* Abase = A + (size_t)m0 * K;
  const __bf16* Bbase = Bt + (size_t)n0 * K;

  for (int k0 = 0; k0 < K; k0 += 32) {
    __syncthreads();
#pragma unroll
    for (int c = 0; c < NCH / 4; ++c) {
      const int ch = c * 4 + w;
      const int r = ch * 16 + lr;
      const __bf16* g = (r < TM) ? (Abase + (size_t)r * K + k0 + lc)
                                 : (Bbase + (size_t)(r - TM) * K + k0 + lc);
      gld_lds16(g, (void*)(lds + ch * 512));
    }
    __syncthreads();
    bf16x8 af[MI], bfr[4];
#pragma unroll
    for (int i = 0; i < MI; ++i)
      af[i] = *(const bf16x8*)&lds[(WR + i * 16 + (lane & 15)) * 32 + (lane >> 4) * 8];
#pragma unroll
    for (int j = 0; j < 4; ++j)
      bfr[j] = *(const bf16x8*)&lds[(TM + WC + j * 16 + (lane & 15)) * 32 + (lane >> 4) * 8];
#pragma unroll
    for (int i = 0; i < MI; ++i)
#pragma unroll
      for (int j = 0; j < 4; ++j)
        acc[i][j] = __builtin_amdgcn_mfma_f32_16x16x32_bf16(af[i], bfr[j], acc[i][j], 0, 0, 0);
  }

  // epilogue: C/D layout col=lane&15, row=(lane>>4)*4+reg (m89/m91-verified)
  const int col0 = n0 + WC + (lane & 15);
#pragma unroll
  for (int j = 0; j < 4; ++j) {
    const int n = col0 + j * 16;
    const float bn = bias[n];
#pragma unroll
    for (int i = 0; i < MI; ++i) {
#pragma unroll
      for (int r = 0; r < 4; ++r) {
        const int m = m0 + WR + i * 16 + (lane >> 4) * 4 + r;
        float v = acc[i][j][r] + bn;
        if (RELU) v = fmaxf(v, 0.f);
        C[(size_t)m * ldc + n] = (OutT)v;
      }
    }
  }
}

// ---------------- MFMA flash attention (bf16 in/out, fp32 softmax & accum) ----------------
// grid (S/64, H, B), 256 threads. QKV: [M][3072] bf16 (q|k|v). O: [M][1024] bf16.
__global__ __launch_bounds__(256) void attention_mfma(const __bf16* __restrict__ QKV,
                                                      __bf16* __restrict__ O) {
  __shared__ __align__(16) __bf16 Ks[64 * 64];   // [key][dk]
  __shared__ __align__(16) __bf16 Vt[64 * 72];   // [dk][key] (+8 pad)
  __shared__ __align__(16) __bf16 Pl[64 * 72];   // [q][key]  (+8 pad), wave-private rows

  const int t = threadIdx.x;
  const int w = t >> 6, lane = t & 63;
  const int quad = lane >> 4, l16 = lane & 15;
  const int q0 = blockIdx.x * 64;
  const int h = blockIdx.y, b = blockIdx.z;
  const size_t rowbase = (size_t)b * Sx;
  const int hoff = h * 64;

  // Q fragments: A[m=l16][k=quad*8+j], held in registers for the whole kernel
  const __bf16* qrow = QKV + (rowbase + q0 + w * 16 + l16) * 3072 + hoff;
  bf16x8 qf0 = *(const bf16x8*)(qrow + quad * 8);
  bf16x8 qf1 = *(const bf16x8*)(qrow + 32 + quad * 8);

  f32x4 oacc[4] = {};
  float mrow[4] = {-1e30f, -1e30f, -1e30f, -1e30f};
  float lrow[4] = {0.f, 0.f, 0.f, 0.f};

  const int vkey = t & 63, vdk0 = (t >> 6) * 16;  // V transpose staging role

  for (int kt = 0; kt < Sx / 64; ++kt) {
    const int k0 = kt * 64;
    __syncthreads();  // previous tile's LDS reads done
    // stage K tile via global_load_lds (wave-uniform dest + lane*16)
#pragma unroll
    for (int c2 = 0; c2 < 2; ++c2) {
      const int c = w + c2 * 4;
      const __bf16* g = QKV + (rowbase + k0 + c * 8 + (lane >> 3)) * 3072 + 1024 + hoff +
                        (lane & 7) * 8;
      gld_lds16(g, (void*)(Ks + c * 512));
    }
    // stage V transposed: Vt[dk][key]
    {
      const __bf16* vrow = QKV + (rowbase + k0 + vkey) * 3072 + 2048 + hoff + vdk0;
      bf16x8 v0 = *(const bf16x8*)vrow;
      bf16x8 v1 = *(const bf16x8*)(vrow + 8);
#pragma unroll
      for (int j = 0; j < 8; ++j) {
        Vt[(vdk0 + j) * 72 + vkey] = v0[j];
        Vt[(vdk0 + 8 + j) * 72 + vkey] = v1[j];
      }
    }
    __syncthreads();

    // QK^T: S[16q x 64k] per wave, 4 col-tiles x 2 k-steps
    f32x4 s[4] = {};
#pragma unroll
    for (int j = 0; j < 4; ++j) {
      bf16x8 b0 = *(const bf16x8*)&Ks[(j * 16 + l16) * 64 + quad * 8];
      bf16x8 b1 = *(const bf16x8*)&Ks[(j * 16 + l16) * 64 + 32 + quad * 8];
      s[j] = __builtin_amdgcn_mfma_f32_16x16x32_bf16(qf0, b0, s[j], 0, 0, 0);
      s[j] = __builtin_amdgcn_mfma_f32_16x16x32_bf16(qf1, b1, s[j], 0, 0, 0);
    }
#pragma unroll
    for (int j = 0; j < 4; ++j) s[j] *= 0.125f;

    // online softmax in registers; reduce across the 16-lane column group
    float alpha[4];
#pragma unroll
    for (int r = 0; r < 4; ++r) {
      float tm = fmaxf(fmaxf(s[0][r], s[1][r]), fmaxf(s[2][r], s[3][r]));
      tm = fmaxf(tm, __shfl_xor(tm, 1));
      tm = fmaxf(tm, __shfl_xor(tm, 2));
      tm = fmaxf(tm, __shfl_xor(tm, 4));
      tm = fmaxf(tm, __shfl_xor(tm, 8));
      float mn = fmaxf(mrow[r], tm);
      alpha[r] = __expf(mrow[r] - mn);
      mrow[r] = mn;
      float rs = 0.f;
#pragma unroll
      for (int j = 0; j < 4; ++j) {
        float p = __expf(s[j][r] - mn);
        s[j][r] = p;
        rs += p;
      }
      rs += __shfl_xor(rs, 1);
      rs += __shfl_xor(rs, 2);
      rs += __shfl_xor(rs, 4);
      rs += __shfl_xor(rs, 8);
      lrow[r] = lrow[r] * alpha[r] + rs;
    }

    // P: C-layout -> LDS (wave-private rows, no barrier needed; DS in-order)
#pragma unroll
    for (int r = 0; r < 4; ++r) {
      const int prow = (w * 16 + quad * 4 + r) * 72;
#pragma unroll
      for (int j = 0; j < 4; ++j) Pl[prow + j * 16 + l16] = (__bf16)s[j][r];
    }

    // rescale O by alpha
#pragma unroll
    for (int j = 0; j < 4; ++j)
#pragma unroll
      for (int r = 0; r < 4; ++r) oacc[j][r] *= alpha[r];

    // PV: P as A-fragments, Vt as B-fragments
    bf16x8 pa0 = *(const bf16x8*)&Pl[(w * 16 + l16) * 72 + quad * 8];
    bf16x8 pa1 = *(const bf16x8*)&Pl[(w * 16 + l16) * 72 + 32 + quad * 8];
#pragma unroll
    for (int j = 0; j < 4; ++j) {
      bf16x8 vb0 = *(const bf16x8*)&Vt[(j * 16 + l16) * 72 + quad * 8];
      bf16x8 vb1 = *(const bf16x8*)&Vt[(j * 16 + l16) * 72 + 32 + quad * 8];
      oacc[j] = __builtin_amdgcn_mfma_f32_16x16x32_bf16(pa0, vb0, oacc[j], 0, 0, 0);
      oacc[j] = __builtin_amdgcn_mfma_f32_16x16x32_bf16(pa1, vb1, oacc[j], 0, 0, 0);
    }
  }

  // epilogue: divide by l, write bf16
#pragma unroll
  for (int r = 0; r < 4; ++r) {
    const float inv = 1.f / lrow[r];
    const size_t orow = (rowbase + q0 + w * 16 + quad * 4 + r) * 1024 + hoff;
#pragma unroll
    for (int j = 0; j < 4; ++j) O[orow + j * 16 + l16] = (__bf16)(oacc[j][r] * inv);
  }
}

// ---------------- fused residual add + LayerNorm, dual fp32+bf16 output ----------------
__global__ void add_ln_kernel(const float* __restrict__ x, const float* __restrict__ r,
                              const float* __restrict__ gamma, const float* __restrict__ beta,
                              float* __restrict__ out, __bf16* __restrict__ outb) {
  int row = blockIdx.x, t = threadIdx.x;
  __shared__ float red[256];
  const float* xr = x + (size_t)row * Dx;
  const float* rr = r + (size_t)row * Dx;
  float v[4];
  float s = 0.f;
#pragma unroll
  for (int i = 0; i < 4; ++i) {
    v[i] = xr[t + i * 256] + rr[t + i * 256];
    s += v[i];
  }
  red[t] = s;
  __syncthreads();
  for (int off = 128; off > 0; off >>= 1) {
    if (t < off) red[t] += red[t + off];
    __syncthreads();
  }
  float mu = red[0] * (1.f / Dx);
  __syncthreads();
  float vs = 0.f;
#pragma unroll
  for (int i = 0; i < 4; ++i) {
    float d = v[i] - mu;
    vs += d * d;
  }
  red[t] = vs;
  __syncthreads();
  for (int off = 128; off > 0; off >>= 1) {
    if (t < off) red[t] += red[t + off];
    __syncthreads();
  }
  float is = rsqrtf(red[0] * (1.f / Dx) + 1e-5f);
  float* orow = out + (size_t)row * Dx;
  __bf16* brow = outb + (size_t)row * Dx;
#pragma unroll
  for (int i = 0; i < 4; ++i) {
    int c = t + i * 256;
    float y = (v[i] - mu) * is * gamma[c] + beta[c];
    orow[c] = y;
    brow[c] = (__bf16)y;
  }
}

extern "C" void kernel_launch(void* const* d_in, const int* in_sizes, int n_in,
                              void* d_out, int out_size, void* d_ws, size_t ws_size,
                              hipStream_t stream) {
  const int* tokens = (const int*)d_in[0];
  const float* emb = (const float*)d_in[1];
  const float* Wq = (const float*)d_in[2];
  const float* bq = (const float*)d_in[3];
  const float* Wk = (const float*)d_in[4];
  const float* bk = (const float*)d_in[5];
  const float* Wv = (const float*)d_in[6];
  const float* bv = (const float*)d_in[7];
  const float* Wo = (const float*)d_in[8];
  const float* bo = (const float*)d_in[9];
  const float* W1 = (const float*)d_in[10];
  const float* b1 = (const float*)d_in[11];
  const float* W2 = (const float*)d_in[12];
  const float* b2 = (const float*)d_in[13];
  const float* gamma = (const float*)d_in[14];
  const float* beta = (const float*)d_in[15];

  const size_t M1 = 1024 * 1024;
  float* ws = (float*)d_ws;
  float* x = ws;                        // 2M f32
  float* tmp = ws + 2 * M1;             // 2M f32
  __bf16* bfr = (__bf16*)(ws + 4 * M1);
  __bf16* xb = bfr;                     // 2M
  __bf16* qkvb = bfr + 2 * M1;          // 6M  [2048][3072]
  __bf16* ob = bfr + 8 * M1;            // 2M
  __bf16* h1b = bfr + 10 * M1;          // 4M  [2048][2048]
  __bf16* WqkvT = bfr + 14 * M1;        // 3M  [3072][1024]
  __bf16* WoT = bfr + 17 * M1;          // 1M
  __bf16* W1T = bfr + 18 * M1;          // 2M
  __bf16* W2T = bfr + 20 * M1;          // 2M
  float* bqkv = (float*)(bfr + 22 * M1);  // 3072 f32

  embed_kernel<<<((size_t)Mx * Dx + 255) / 256, 256, 0, stream>>>(tokens, emb, x, xb);

  dim3 tb(32, 8);

  for (int l = 0; l < Lx; ++l) {
    const float* Wq_l = Wq + (size_t)l * Dx * Dx;
    const float* Wk_l = Wk + (size_t)l * Dx * Dx;
    const float* Wv_l = Wv + (size_t)l * Dx * Dx;
    const float* Wo_l = Wo + (size_t)l * Dx * Dx;
    const float* W1_l = W1 + (size_t)l * Dx * FFx;
    const float* W2_l = W2 + (size_t)l * FFx * Dx;
    const float* bo_l = bo + (size_t)l * Dx;
    const float* b1_l = b1 + (size_t)l * FFx;
    const float* b2_l = b2 + (size_t)l * Dx;
    const float* g_l = gamma + (size_t)l * Dx;
    const float* be_l = beta + (size_t)l * Dx;

    // weight prep (bf16, transposed)
    transpose_to_bf16<<<dim3(32, 32), tb, 0, stream>>>(Wq_l, WqkvT, Dx, Dx);
    transpose_to_bf16<<<dim3(32, 32), tb, 0, stream>>>(Wk_l, WqkvT + M1, Dx, Dx);
    transpose_to_bf16<<<dim3(32, 32), tb, 0, stream>>>(Wv_l, WqkvT + 2 * M1, Dx, Dx);
    transpose_to_bf16<<<dim3(32, 32), tb, 0, stream>>>(Wo_l, WoT, Dx, Dx);
    transpose_to_bf16<<<dim3(64, 32), tb, 0, stream>>>(W1_l, W1T, Dx, FFx);
    transpose_to_bf16<<<dim3(32, 64), tb, 0, stream>>>(W2_l, W2T, FFx, Dx);
    concat3_kernel<<<12, 256, 0, stream>>>(bq + (size_t)l * Dx, bk + (size_t)l * Dx,
                                           bv + (size_t)l * Dx, bqkv);

    // QKV fused GEMM -> bf16
    gemm_bt<128, false, __bf16><<<dim3(3072 / 128, Mx / 128), 256, 0, stream>>>(
        xb, WqkvT, bqkv, qkvb, Dx, 3072);

    attention_mfma<<<dim3(Sx / 64, Hx, Bx), 256, 0, stream>>>(qkvb, ob);

    // output projection -> fp32, then add+LN (dual out)
    gemm_bt<64, false, float><<<dim3(Dx / 128, Mx / 64), 256, 0, stream>>>(
        ob, WoT, bo_l, tmp, Dx, Dx);
    add_ln_kernel<<<Mx, 256, 0, stream>>>(x, tmp, g_l, be_l, x, xb);

    // FF
    gemm_bt<128, true, __bf16><<<dim3(FFx / 128, Mx / 128), 256, 0, stream>>>(
        xb, W1T, b1_l, h1b, Dx, FFx);
    gemm_bt<64, false, float><<<dim3(Dx / 128, Mx / 64), 256, 0, stream>>>(
        h1b, W2T, b2_l, tmp, FFx, Dx);
    add_ln_kernel<<<Mx, 256, 0, stream>>>(x, tmp, g_l, be_l, x, xb);
  }

  hipMemcpyAsync(d_out, x, 2 * M1 * sizeof(float), hipMemcpyDeviceToDevice, stream);
}